// Round 17
// baseline (2542.001 us; speedup 1.0000x reference)
//
#include <hip/hip_runtime.h>
#include <stdint.h>

typedef __bf16 bf16x8 __attribute__((ext_vector_type(8)));
typedef float  f32x4  __attribute__((ext_vector_type(4)));
typedef float  f32x16 __attribute__((ext_vector_type(16)));
typedef unsigned short u16;

// ---- workspace layout (bytes) ----
#define WCT_OFF   0u          // 144*256 bf16 = 73728   (W^T, fused Wq|Wk|Wv)
#define SC_OFF    73728u      // 144 f32 BN scale
#define SH_OFF    74304u      // 144 f32 BN shift
#define BST_OFF   75008u      // 23 * 16384 B (2-window conv B frags, frag-lane order)
#define ZB_OFF    524288u     // 4096 B of zeros (OOB guard for img staging)
#define MSUM_OFF  640256u     // 16*16*2 f32 (softmax max, 1/sum)
#define LCB_OFF   642304u     // 16*16*64 f32 (Lc + pos_b)
#define QP_OFF    707840u     // 16*4096*64 bf16 (q, BN'd, [b][pos][ch])
#define KT_OFF    9096448u    // 16*16*4096 bf16 (k, [b][ch][pos])
#define VT_OFF    11193600u   // 16*64*4096 bf16 (v, BN'd, [b][ch][pos] = per-v image)
#define P_OFF     19582208u   // 16*16*4096 bf16 (unnormalized softmax exp)

// ------------------------------------------------------------------
// Kernel P (parallelized): grid 168.
// ------------------------------------------------------------------
__global__ void kP(const float* Wq, const float* Wk, const float* Wv,
                   const float* gq, const float* bq, const float* mq, const float* vq,
                   const float* gv, const float* bv, const float* mv, const float* vvar,
                   const float* pw, char* ws) {
  int t = threadIdx.x;
  int blk = blockIdx.x;
  if (blk < 144) {
    int n = blk, c = t;
    float val;
    if (n < 64)      val = Wq[c * 64 + n];
    else if (n < 80) val = Wk[c * 16 + (n - 64)];
    else             val = Wv[c * 64 + (n - 80)];
    ((__bf16*)(ws + WCT_OFF))[n * 256 + c] = (__bf16)val;
  } else if (blk == 144) {
    if (t < 144) {
      float s, sh;
      if (t < 64)      { s = gq[t] * rsqrtf(vq[t] + 1e-3f); sh = bq[t] - mq[t] * s; }
      else if (t < 80) { s = 1.f; sh = 0.f; }
      else { int i = t - 80; s = gv[i] * rsqrtf(vvar[i] + 1e-3f); sh = bv[i] - mv[i] * s; }
      ((float*)(ws + SC_OFF))[t] = s;
      ((float*)(ws + SH_OFF))[t] = sh;
    }
    f32x4 fz;
    fz[0] = 0.f; fz[1] = 0.f; fz[2] = 0.f; fz[3] = 0.f;
    *(f32x4*)(ws + ZB_OFF + t * 16) = fz;     // 256*16 = 4096 B of zeros
  } else {
    int dy = blk - 145;                    // 0..22
    __bf16* bst = (__bf16*)(ws + BST_OFF) + dy * 8192;
    for (int i = 0; i < 32; ++i) {
      int idx = i * 256 + t;               // < 8192
      int nt = idx >> 10;
      int w2 = (idx >> 9) & 1;
      int l  = (idx >> 3) & 63;
      int e  = idx & 7;
      int n  = nt * 32 + (l & 31);
      int xr = n >> 4, kch = n & 15;
      int o1 = (2 * nt + 5) & ~7;
      int j  = o1 + w2 * 16 + (l >> 5) * 8 + e;
      int dxw = j - xr - 5;
      float val = (dxw >= 0 && dxw < 23) ? pw[(dy * 23 + dxw) * 16 + kch] : 0.f;
      bst[idx] = (__bf16)val;
    }
  }
}

// ------------------------------------------------------------------
// Kernel A: fused q/k/v projections + BN, MFMA 16x16x32.
// Grid 1024, M=64/block (4 blocks/CU).
// ------------------------------------------------------------------
__global__ __launch_bounds__(256) void kA(const float* x, char* ws) {
  __shared__ __align__(16) u16 qlds[64 * 72];   // 64 pos x 64ch (pad 72), 9216B
  int t = threadIdx.x, w = t >> 6, l = t & 63;
  int m0 = blockIdx.x * 64;
  int b = m0 >> 12;
  int posb = m0 & 4095;
  const __bf16* wct = (const __bf16*)(ws + WCT_OFF);
  const float* sc = (const float*)(ws + SC_OFF);
  const float* sh = (const float*)(ws + SH_OFF);
  __bf16* qp = (__bf16*)(ws + QP_OFF);
  __bf16* kt = (__bf16*)(ws + KT_OFF);
  __bf16* vt = (__bf16*)(ws + VT_OFF);

  int rl = l & 15;
  int kg = l >> 4;

  f32x4 acc[9];
#pragma unroll
  for (int nf = 0; nf < 9; ++nf)
#pragma unroll
    for (int q = 0; q < 4; ++q) acc[nf][q] = 0.f;

  for (int ks = 0; ks < 8; ++ks) {
    int m = m0 + w * 16 + rl;
    const float* xp = x + (size_t)m * 256 + ks * 32 + kg * 8;
    f32x4 v0 = *(const f32x4*)xp;
    f32x4 v1 = *(const f32x4*)(xp + 4);
    bf16x8 a;
    a[0] = (__bf16)v0[0]; a[1] = (__bf16)v0[1]; a[2] = (__bf16)v0[2]; a[3] = (__bf16)v0[3];
    a[4] = (__bf16)v1[0]; a[5] = (__bf16)v1[1]; a[6] = (__bf16)v1[2]; a[7] = (__bf16)v1[3];
#pragma unroll
    for (int nf = 0; nf < 9; ++nf) {
      bf16x8 bfr = *(const bf16x8*)(wct + (nf * 16 + rl) * 256 + ks * 32 + kg * 8);
      acc[nf] = __builtin_amdgcn_mfma_f32_16x16x32_bf16(a, bfr, acc[nf], 0, 0, 0);
    }
  }

#pragma unroll
  for (int nf = 0; nf < 9; ++nf) {
    int ch = nf * 16 + rl;
    float s = sc[ch], shv = sh[ch];
    int pbase = w * 16 + kg * 4;
    union { __bf16 h[4]; uint2 u; } pk;
#pragma unroll
    for (int r = 0; r < 4; ++r) pk.h[r] = (__bf16)(acc[nf][r] * s + shv);
    if (ch < 64) {
#pragma unroll
      for (int r = 0; r < 4; ++r)
        qlds[(pbase + r) * 72 + ch] = ((u16*)&pk.h[r])[0];
    } else if (ch < 80) {
      *(uint2*)(kt + (size_t)(b * 16 + ch - 64) * 4096 + posb + pbase) = pk.u;
    } else {
      *(uint2*)(vt + (size_t)(b * 64 + ch - 80) * 4096 + posb + pbase) = pk.u;
    }
  }
  __syncthreads();
  // dense readback: 512 chunks of 8 bf16
#pragma unroll
  for (int i = 0; i < 2; ++i) {
    int chunk = t + i * 256;
    int row = chunk >> 3, seg = chunk & 7;
    bf16x8 vq_ = *(const bf16x8*)(qlds + row * 72 + seg * 8);
    *(bf16x8*)(qp + (size_t)(b * 4096 + posb + row) * 64 + seg * 8) = vq_;
  }
}

// ------------------------------------------------------------------
// Kernel B1: per (b, k-channel) softmax max & 1/sum over 4096 positions.
// Also stores unnormalized P = exp(kt - mx) as bf16 (computed once).
// ------------------------------------------------------------------
__global__ void kB1(char* ws) {
  __shared__ float red[256];
  int t = threadIdx.x;
  int b = blockIdx.x >> 4, kk = blockIdx.x & 15;
  const __bf16* kt = (const __bf16*)(ws + KT_OFF) + (size_t)(b * 16 + kk) * 4096;
  __bf16* P = (__bf16*)(ws + P_OFF) + (size_t)(b * 16 + kk) * 4096;
  float v[16];
  bf16x8 c0 = *(const bf16x8*)(kt + t * 16);
  bf16x8 c1 = *(const bf16x8*)(kt + t * 16 + 8);
#pragma unroll
  for (int i = 0; i < 8; ++i) { v[i] = (float)c0[i]; v[8 + i] = (float)c1[i]; }
  float mx = v[0];
#pragma unroll
  for (int i = 1; i < 16; ++i) mx = fmaxf(mx, v[i]);
  red[t] = mx; __syncthreads();
  for (int s = 128; s > 0; s >>= 1) { if (t < s) red[t] = fmaxf(red[t], red[t + s]); __syncthreads(); }
  mx = red[0]; __syncthreads();
  float se = 0.f;
  union { __bf16 h[8]; uint4 u; } p0, p1;
#pragma unroll
  for (int i = 0; i < 8; ++i) { float e = expf(v[i] - mx); se += e; p0.h[i] = (__bf16)e; }
#pragma unroll
  for (int i = 0; i < 8; ++i) { float e = expf(v[8 + i] - mx); se += e; p1.h[i] = (__bf16)e; }
  *(uint4*)(P + t * 16) = p0.u;
  *(uint4*)(P + t * 16 + 8) = p1.u;
  red[t] = se; __syncthreads();
  for (int s = 128; s > 0; s >>= 1) { if (t < s) red[t] += red[t + s]; __syncthreads(); }
  if (t == 0) {
    float* ms = (float*)(ws + MSUM_OFF);
    ms[(b * 16 + kk) * 2] = mx;
    ms[(b * 16 + kk) * 2 + 1] = 1.f / red[0];
  }
}

// ------------------------------------------------------------------
// Kernel B2: LcB[b][k][v] = (sum_n P[k][n]*v[v][n]) * rsum + pos_b[k]
// ------------------------------------------------------------------
__global__ __launch_bounds__(256) void kB2(char* ws, const float* pos_b) {
  __shared__ float red[16][256];
  int t = threadIdx.x;
  int b = blockIdx.x >> 6, v = blockIdx.x & 63;
  const __bf16* P = (const __bf16*)(ws + P_OFF) + (size_t)b * 16 * 4096;
  const __bf16* vt = (const __bf16*)(ws + VT_OFF) + (size_t)(b * 64 + v) * 4096;
  const float* ms = (const float*)(ws + MSUM_OFF) + b * 32;
  float acc[16];
#pragma unroll
  for (int i = 0; i < 16; ++i) acc[i] = 0.f;
  for (int c = 0; c < 16; ++c) {
    int p = c * 256 + t;
    float vv = (float)vt[p];
#pragma unroll
    for (int i = 0; i < 16; ++i)
      acc[i] += (float)P[i * 4096 + p] * vv;
  }
#pragma unroll
  for (int i = 0; i < 16; ++i) red[i][t] = acc[i];
  __syncthreads();
  for (int s = 128; s > 0; s >>= 1) {
    if (t < s) {
#pragma unroll
      for (int i = 0; i < 16; ++i) red[i][t] += red[i][t + s];
    }
    __syncthreads();
  }
  if (t < 16) {
    float* lcb = (float*)(ws + LCB_OFF);
    lcb[(b * 16 + t) * 64 + v] = red[t][0] * ms[2 * t + 1] + pos_b[t];
  }
}

// ------------------------------------------------------------------
// Kernel C (FUSED conv + combine), R17 = exact R13 body (4-slot ring,
// 36.8KB LDS, vmcnt(1), 1 barrier/dy, af direct from L2) but
// __launch_bounds__(512, 8): 4 blocks/CU (147KB LDS), 8 waves/SIMD —
// doubles TLP to cover the af/img L2 latency.
// ------------------------------------------------------------------
__global__ __launch_bounds__(512, 8) void kC(char* ws, float* out) {
  __shared__ __align__(16) u16 img[4][64][64];    // 32768 B  [slot][v][col]
  __shared__ __align__(16) u16 qt[2048];          // 4096 B   [yy][x16][ch64]
  int t = threadIdx.x, w = t >> 6, l = t & 63;
  int bid = blockIdx.x;
  int swz = (bid & 7) * 256 + (bid >> 3);         // 2048 = 8 XCD x 256
  int b = swz >> 7;
  int rest = swz & 127;
  int yp = rest >> 2, xt = rest & 3;
  int y0 = yp * 2, x0g = xt * 16;
  const __bf16* vt  = (const __bf16*)(ws + VT_OFF);
  const __bf16* qp  = (const __bf16*)(ws + QP_OFF);
  const float*  lcb = (const float*)(ws + LCB_OFF) + b * 1024;
  const char*   bstc = (const char*)(ws + BST_OFF);
  const char*   zb   = (const char*)(ws + ZB_OFF) + (t & 255) * 16;

  int yy = w >> 2, ntp = w & 3;
  int hh = l >> 5;
  int o1_8 = ((4 * ntp + 5) & ~7) >> 3;    // shared window base / 8 for the nt-pair

  // img staging lane map: LDS linear [sv][sc8*8]; global chunk = sc8 ^ (sv&7)
  int sv = t >> 3, sc8 = t & 7;
  int sgx = x0g - 16 + (sc8 ^ (sv & 7)) * 8;
  bool sokx = (sgx >= 0 && sgx < 64);
  const char* vsrc = (const char*)(vt + (size_t)(b * 64 + sv) * 4096 + sgx);

#define STAGE_IMG(slot, rowv) do {                                             \
    int _r = (rowv);                                                           \
    const char* _s = (sokx && _r >= 0 && _r < 64) ? (vsrc + _r * 128) : zb;    \
    __builtin_amdgcn_global_load_lds(                                          \
      (const __attribute__((address_space(1))) void*)_s,                       \
      (__attribute__((address_space(3))) void*)((char*)&img[0][0][0] + (slot) * 8192 + w * 1024), \
      16, 0, 0);                                                               \
  } while (0)

  // ---- prologue: img slots 0,1,2; q tile (only ds_write, drained) ----
  STAGE_IMG(0, y0 - 11);
  STAGE_IMG(1, y0 - 10);
  STAGE_IMG(2, y0 - 9);
  {
    int f0 = t * 4;
    int qyy = f0 >> 10, qx = (f0 >> 6) & 15, qch = f0 & 63;
    *(uint2*)&qt[f0] =
      *(const uint2*)(qp + (size_t)(b * 4096 + (y0 + qyy) * 64 + x0g + qx) * 64 + qch);
  }
  asm volatile("s_waitcnt lgkmcnt(0)" ::: "memory");

  // af byte offsets within one dy-block of bst (lane-linear, coalesced)
  int afoff[2][2];
#pragma unroll
  for (int j = 0; j < 2; ++j)
#pragma unroll
    for (int w2 = 0; w2 < 2; ++w2)
      afoff[j][w2] = ((((2 * ntp + j) * 2 + w2) * 64) + l) * 16;

  f32x16 acc[2][2];
#pragma unroll
  for (int mf = 0; mf < 2; ++mf)
#pragma unroll
    for (int j = 0; j < 2; ++j)
#pragma unroll
      for (int q = 0; q < 16; ++q) acc[mf][j][q] = 0.f;

  for (int dy = 0; dy < 23; ++dy) {
    if (dy < 22) {
      asm volatile("s_waitcnt vmcnt(1)" ::: "memory");
    } else {
      asm volatile("s_waitcnt vmcnt(0)" ::: "memory");
    }
    __builtin_amdgcn_s_barrier();
    __builtin_amdgcn_sched_barrier(0);
    asm volatile("" ::: "memory");

    // stage img 3 ahead (slot not read in this barrier interval)
    if (dy < 21) STAGE_IMG((dy + 3) & 3, y0 + dy - 8);

    // af direct from global (L2-hit; compiler inserts the waits)
    const char* bdy = bstc + dy * 16384;
    bf16x8 af[2][2], bi[2][2];
#pragma unroll
    for (int j = 0; j < 2; ++j)
#pragma unroll
      for (int w2 = 0; w2 < 2; ++w2)
        af[j][w2] = *(const bf16x8*)(bdy + afoff[j][w2]);

    int rsl = (dy + yy) & 3;
#pragma unroll
    for (int mf = 0; mf < 2; ++mf) {
      int v = mf * 32 + (l & 31);
#pragma unroll
      for (int w2 = 0; w2 < 2; ++w2)
        bi[mf][w2] = *(const bf16x8*)(&img[rsl][v][((o1_8 + w2 * 2 + hh) ^ (v & 7)) * 8]);
    }
#pragma unroll
    for (int w2 = 0; w2 < 2; ++w2)
#pragma unroll
      for (int j = 0; j < 2; ++j) {
        acc[0][j] = __builtin_amdgcn_mfma_f32_32x32x16_bf16(af[j][w2], bi[0][w2], acc[0][j], 0, 0, 0);
        acc[1][j] = __builtin_amdgcn_mfma_f32_32x32x16_bf16(af[j][w2], bi[1][w2], acc[1][j], 0, 0, 0);
      }
  }
#undef STAGE_IMG

  // ---- fused epilogue: Y = sum_k q*(Lc + Lp), k lives in acc reg index ----
  float lc[2][16];
#pragma unroll
  for (int mf = 0; mf < 2; ++mf)
#pragma unroll
    for (int r = 0; r < 16; ++r) {
      int k = (r & 3) + 8 * ((r >> 2) & 1) + 4 * hh;
      lc[mf][r] = lcb[k * 64 + mf * 32 + (l & 31)];
    }
  size_t obase = ((size_t)b * 4096 + (y0 + yy) * 64 + x0g) * 256;
#pragma unroll
  for (int j = 0; j < 2; ++j) {
#pragma unroll
    for (int xh = 0; xh < 2; ++xh) {
      int x_local = 2 * (2 * ntp + j) + xh;
      const u16* qrow = &qt[(yy * 16 + x_local) * 64];
#pragma unroll
      for (int h = 0; h < 4; ++h) {
        float s0 = 0.f, s1 = 0.f;
#pragma unroll
        for (int r8 = 0; r8 < 8; ++r8) {
          int r = xh * 8 + r8;
          int k = (r8 & 3) + 8 * (r8 >> 2) + 4 * hh;
          float qv = (float)(*(const __bf16*)&qrow[h * 16 + k]);   // LDS broadcast
          s0 += qv * (acc[0][j][r] + lc[0][r]);
          s1 += qv * (acc[1][j][r] + lc[1][r]);
        }
        s0 += __shfl_xor(s0, 32);
        s1 += __shfl_xor(s1, 32);
        float val = (l >= 32) ? s1 : s0;           // ch = h*64 + l, v = l
        out[obase + (size_t)x_local * 256 + h * 64 + l] = val;
      }
    }
  }
}

extern "C" void kernel_launch(void* const* d_in, const int* in_sizes, int n_in,
                              void* d_out, int out_size, void* d_ws, size_t ws_size,
                              hipStream_t stream) {
  const float* x   = (const float*)d_in[0];
  const float* Wq  = (const float*)d_in[1];
  const float* Wk  = (const float*)d_in[2];
  const float* Wv  = (const float*)d_in[3];
  const float* gq  = (const float*)d_in[4];
  const float* bq  = (const float*)d_in[5];
  const float* mq  = (const float*)d_in[6];
  const float* vq  = (const float*)d_in[7];
  const float* gv  = (const float*)d_in[8];
  const float* bv  = (const float*)d_in[9];
  const float* mv  = (const float*)d_in[10];
  const float* vvr = (const float*)d_in[11];
  const float* pw  = (const float*)d_in[12];
  const float* pb  = (const float*)d_in[13];
  char* ws = (char*)d_ws;
  float* out = (float*)d_out;

  hipLaunchKernelGGL(kP, dim3(168), dim3(256), 0, stream,
                     Wq, Wk, Wv, gq, bq, mq, vq, gv, bv, mv, vvr, pw, ws);
  hipLaunchKernelGGL(kA, dim3(1024), dim3(256), 0, stream, x, ws);
  hipLaunchKernelGGL(kB1, dim3(256), dim3(256), 0, stream, ws);
  hipLaunchKernelGGL(kB2, dim3(1024), dim3(256), 0, stream, ws, pb);
  hipLaunchKernelGGL(kC, dim3(2048), dim3(512), 0, stream, ws, out);
}

// Round 18
// 845.475 us; speedup vs baseline: 3.0066x; 3.0066x over previous
//
#include <hip/hip_runtime.h>
#include <stdint.h>

typedef __bf16 bf16x8 __attribute__((ext_vector_type(8)));
typedef float  f32x4  __attribute__((ext_vector_type(4)));
typedef float  f32x16 __attribute__((ext_vector_type(16)));
typedef unsigned short u16;

// ---- workspace layout (bytes) ----
#define WCT_OFF   0u          // 144*256 bf16 = 73728   (W^T, fused Wq|Wk|Wv)
#define SC_OFF    73728u      // 144 f32 BN scale
#define SH_OFF    74304u      // 144 f32 BN shift
#define BST_OFF   75008u      // 23 * 16384 B (2-window conv B frags, frag-lane order)
#define ZB_OFF    524288u     // 4096 B of zeros (OOB guard for img staging)
#define MSUM_OFF  640256u     // 16*16*2 f32 (softmax max, 1/sum)
#define LCB_OFF   642304u     // 16*16*64 f32 (Lc + pos_b)
#define QP_OFF    707840u     // 16*4096*64 bf16 (q, BN'd, [b][pos][ch])
#define KT_OFF    9096448u    // 16*16*4096 bf16 (k, [b][ch][pos])
#define VT_OFF    11193600u   // 16*64*4096 bf16 (v, BN'd, [b][ch][pos] = per-v image)
#define P_OFF     19582208u   // 16*16*4096 bf16 (unnormalized softmax exp)

// ------------------------------------------------------------------
// Kernel P (parallelized): grid 168.
// ------------------------------------------------------------------
__global__ void kP(const float* Wq, const float* Wk, const float* Wv,
                   const float* gq, const float* bq, const float* mq, const float* vq,
                   const float* gv, const float* bv, const float* mv, const float* vvar,
                   const float* pw, char* ws) {
  int t = threadIdx.x;
  int blk = blockIdx.x;
  if (blk < 144) {
    int n = blk, c = t;
    float val;
    if (n < 64)      val = Wq[c * 64 + n];
    else if (n < 80) val = Wk[c * 16 + (n - 64)];
    else             val = Wv[c * 64 + (n - 80)];
    ((__bf16*)(ws + WCT_OFF))[n * 256 + c] = (__bf16)val;
  } else if (blk == 144) {
    if (t < 144) {
      float s, sh;
      if (t < 64)      { s = gq[t] * rsqrtf(vq[t] + 1e-3f); sh = bq[t] - mq[t] * s; }
      else if (t < 80) { s = 1.f; sh = 0.f; }
      else { int i = t - 80; s = gv[i] * rsqrtf(vvar[i] + 1e-3f); sh = bv[i] - mv[i] * s; }
      ((float*)(ws + SC_OFF))[t] = s;
      ((float*)(ws + SH_OFF))[t] = sh;
    }
    f32x4 fz;
    fz[0] = 0.f; fz[1] = 0.f; fz[2] = 0.f; fz[3] = 0.f;
    *(f32x4*)(ws + ZB_OFF + t * 16) = fz;     // 256*16 = 4096 B of zeros
  } else {
    int dy = blk - 145;                    // 0..22
    __bf16* bst = (__bf16*)(ws + BST_OFF) + dy * 8192;
    for (int i = 0; i < 32; ++i) {
      int idx = i * 256 + t;               // < 8192
      int nt = idx >> 10;
      int w2 = (idx >> 9) & 1;
      int l  = (idx >> 3) & 63;
      int e  = idx & 7;
      int n  = nt * 32 + (l & 31);
      int xr = n >> 4, kch = n & 15;
      int o1 = (2 * nt + 5) & ~7;
      int j  = o1 + w2 * 16 + (l >> 5) * 8 + e;
      int dxw = j - xr - 5;
      float val = (dxw >= 0 && dxw < 23) ? pw[(dy * 23 + dxw) * 16 + kch] : 0.f;
      bst[idx] = (__bf16)val;
    }
  }
}

// ------------------------------------------------------------------
// Kernel A: fused q/k/v projections + BN, MFMA 16x16x32.
// Grid 1024, M=64/block (4 blocks/CU).
// ------------------------------------------------------------------
__global__ __launch_bounds__(256) void kA(const float* x, char* ws) {
  __shared__ __align__(16) u16 qlds[64 * 72];   // 64 pos x 64ch (pad 72), 9216B
  int t = threadIdx.x, w = t >> 6, l = t & 63;
  int m0 = blockIdx.x * 64;
  int b = m0 >> 12;
  int posb = m0 & 4095;
  const __bf16* wct = (const __bf16*)(ws + WCT_OFF);
  const float* sc = (const float*)(ws + SC_OFF);
  const float* sh = (const float*)(ws + SH_OFF);
  __bf16* qp = (__bf16*)(ws + QP_OFF);
  __bf16* kt = (__bf16*)(ws + KT_OFF);
  __bf16* vt = (__bf16*)(ws + VT_OFF);

  int rl = l & 15;
  int kg = l >> 4;

  f32x4 acc[9];
#pragma unroll
  for (int nf = 0; nf < 9; ++nf)
#pragma unroll
    for (int q = 0; q < 4; ++q) acc[nf][q] = 0.f;

  for (int ks = 0; ks < 8; ++ks) {
    int m = m0 + w * 16 + rl;
    const float* xp = x + (size_t)m * 256 + ks * 32 + kg * 8;
    f32x4 v0 = *(const f32x4*)xp;
    f32x4 v1 = *(const f32x4*)(xp + 4);
    bf16x8 a;
    a[0] = (__bf16)v0[0]; a[1] = (__bf16)v0[1]; a[2] = (__bf16)v0[2]; a[3] = (__bf16)v0[3];
    a[4] = (__bf16)v1[0]; a[5] = (__bf16)v1[1]; a[6] = (__bf16)v1[2]; a[7] = (__bf16)v1[3];
#pragma unroll
    for (int nf = 0; nf < 9; ++nf) {
      bf16x8 bfr = *(const bf16x8*)(wct + (nf * 16 + rl) * 256 + ks * 32 + kg * 8);
      acc[nf] = __builtin_amdgcn_mfma_f32_16x16x32_bf16(a, bfr, acc[nf], 0, 0, 0);
    }
  }

#pragma unroll
  for (int nf = 0; nf < 9; ++nf) {
    int ch = nf * 16 + rl;
    float s = sc[ch], shv = sh[ch];
    int pbase = w * 16 + kg * 4;
    union { __bf16 h[4]; uint2 u; } pk;
#pragma unroll
    for (int r = 0; r < 4; ++r) pk.h[r] = (__bf16)(acc[nf][r] * s + shv);
    if (ch < 64) {
#pragma unroll
      for (int r = 0; r < 4; ++r)
        qlds[(pbase + r) * 72 + ch] = ((u16*)&pk.h[r])[0];
    } else if (ch < 80) {
      *(uint2*)(kt + (size_t)(b * 16 + ch - 64) * 4096 + posb + pbase) = pk.u;
    } else {
      *(uint2*)(vt + (size_t)(b * 64 + ch - 80) * 4096 + posb + pbase) = pk.u;
    }
  }
  __syncthreads();
  // dense readback: 512 chunks of 8 bf16
#pragma unroll
  for (int i = 0; i < 2; ++i) {
    int chunk = t + i * 256;
    int row = chunk >> 3, seg = chunk & 7;
    bf16x8 vq_ = *(const bf16x8*)(qlds + row * 72 + seg * 8);
    *(bf16x8*)(qp + (size_t)(b * 4096 + posb + row) * 64 + seg * 8) = vq_;
  }
}

// ------------------------------------------------------------------
// Kernel B1: per (b, k-channel) softmax max & 1/sum over 4096 positions.
// Also stores unnormalized P = exp(kt - mx) as bf16 (computed once).
// ------------------------------------------------------------------
__global__ void kB1(char* ws) {
  __shared__ float red[256];
  int t = threadIdx.x;
  int b = blockIdx.x >> 4, kk = blockIdx.x & 15;
  const __bf16* kt = (const __bf16*)(ws + KT_OFF) + (size_t)(b * 16 + kk) * 4096;
  __bf16* P = (__bf16*)(ws + P_OFF) + (size_t)(b * 16 + kk) * 4096;
  float v[16];
  bf16x8 c0 = *(const bf16x8*)(kt + t * 16);
  bf16x8 c1 = *(const bf16x8*)(kt + t * 16 + 8);
#pragma unroll
  for (int i = 0; i < 8; ++i) { v[i] = (float)c0[i]; v[8 + i] = (float)c1[i]; }
  float mx = v[0];
#pragma unroll
  for (int i = 1; i < 16; ++i) mx = fmaxf(mx, v[i]);
  red[t] = mx; __syncthreads();
  for (int s = 128; s > 0; s >>= 1) { if (t < s) red[t] = fmaxf(red[t], red[t + s]); __syncthreads(); }
  mx = red[0]; __syncthreads();
  float se = 0.f;
  union { __bf16 h[8]; uint4 u; } p0, p1;
#pragma unroll
  for (int i = 0; i < 8; ++i) { float e = expf(v[i] - mx); se += e; p0.h[i] = (__bf16)e; }
#pragma unroll
  for (int i = 0; i < 8; ++i) { float e = expf(v[8 + i] - mx); se += e; p1.h[i] = (__bf16)e; }
  *(uint4*)(P + t * 16) = p0.u;
  *(uint4*)(P + t * 16 + 8) = p1.u;
  red[t] = se; __syncthreads();
  for (int s = 128; s > 0; s >>= 1) { if (t < s) red[t] += red[t + s]; __syncthreads(); }
  if (t == 0) {
    float* ms = (float*)(ws + MSUM_OFF);
    ms[(b * 16 + kk) * 2] = mx;
    ms[(b * 16 + kk) * 2 + 1] = 1.f / red[0];
  }
}

// ------------------------------------------------------------------
// Kernel B2: LcB[b][k][v] = (sum_n P[k][n]*v[v][n]) * rsum + pos_b[k]
// ------------------------------------------------------------------
__global__ __launch_bounds__(256) void kB2(char* ws, const float* pos_b) {
  __shared__ float red[16][256];
  int t = threadIdx.x;
  int b = blockIdx.x >> 6, v = blockIdx.x & 63;
  const __bf16* P = (const __bf16*)(ws + P_OFF) + (size_t)b * 16 * 4096;
  const __bf16* vt = (const __bf16*)(ws + VT_OFF) + (size_t)(b * 64 + v) * 4096;
  const float* ms = (const float*)(ws + MSUM_OFF) + b * 32;
  float acc[16];
#pragma unroll
  for (int i = 0; i < 16; ++i) acc[i] = 0.f;
  for (int c = 0; c < 16; ++c) {
    int p = c * 256 + t;
    float vv = (float)vt[p];
#pragma unroll
    for (int i = 0; i < 16; ++i)
      acc[i] += (float)P[i * 4096 + p] * vv;
  }
#pragma unroll
  for (int i = 0; i < 16; ++i) red[i][t] = acc[i];
  __syncthreads();
  for (int s = 128; s > 0; s >>= 1) {
    if (t < s) {
#pragma unroll
      for (int i = 0; i < 16; ++i) red[i][t] += red[i][t + s];
    }
    __syncthreads();
  }
  if (t < 16) {
    float* lcb = (float*)(ws + LCB_OFF);
    lcb[(b * 16 + t) * 64 + v] = red[t][0] * ms[2 * t + 1] + pos_b[t];
  }
}

// ------------------------------------------------------------------
// Kernel C (FUSED conv + combine), R18 = exact R13 body (4-slot ring,
// 36.8KB LDS, vmcnt(1), 1 barrier/dy, af direct from L2) with
// __launch_bounds__(512, 6): VGPR budget 85 >= R13's natural 64+temps,
// 3 blocks/CU (110KB LDS), 6 waves/SIMD — 1.5x TLP without spilling.
// (R17's (512,8) forced 64-VGPR budget -> spill catastrophe; reverted.)
// ------------------------------------------------------------------
__global__ __launch_bounds__(512, 6) void kC(char* ws, float* out) {
  __shared__ __align__(16) u16 img[4][64][64];    // 32768 B  [slot][v][col]
  __shared__ __align__(16) u16 qt[2048];          // 4096 B   [yy][x16][ch64]
  int t = threadIdx.x, w = t >> 6, l = t & 63;
  int bid = blockIdx.x;
  int swz = (bid & 7) * 256 + (bid >> 3);         // 2048 = 8 XCD x 256
  int b = swz >> 7;
  int rest = swz & 127;
  int yp = rest >> 2, xt = rest & 3;
  int y0 = yp * 2, x0g = xt * 16;
  const __bf16* vt  = (const __bf16*)(ws + VT_OFF);
  const __bf16* qp  = (const __bf16*)(ws + QP_OFF);
  const float*  lcb = (const float*)(ws + LCB_OFF) + b * 1024;
  const char*   bstc = (const char*)(ws + BST_OFF);
  const char*   zb   = (const char*)(ws + ZB_OFF) + (t & 255) * 16;

  int yy = w >> 2, ntp = w & 3;
  int hh = l >> 5;
  int o1_8 = ((4 * ntp + 5) & ~7) >> 3;    // shared window base / 8 for the nt-pair

  // img staging lane map: LDS linear [sv][sc8*8]; global chunk = sc8 ^ (sv&7)
  int sv = t >> 3, sc8 = t & 7;
  int sgx = x0g - 16 + (sc8 ^ (sv & 7)) * 8;
  bool sokx = (sgx >= 0 && sgx < 64);
  const char* vsrc = (const char*)(vt + (size_t)(b * 64 + sv) * 4096 + sgx);

#define STAGE_IMG(slot, rowv) do {                                             \
    int _r = (rowv);                                                           \
    const char* _s = (sokx && _r >= 0 && _r < 64) ? (vsrc + _r * 128) : zb;    \
    __builtin_amdgcn_global_load_lds(                                          \
      (const __attribute__((address_space(1))) void*)_s,                       \
      (__attribute__((address_space(3))) void*)((char*)&img[0][0][0] + (slot) * 8192 + w * 1024), \
      16, 0, 0);                                                               \
  } while (0)

  // ---- prologue: img slots 0,1,2; q tile (only ds_write, drained) ----
  STAGE_IMG(0, y0 - 11);
  STAGE_IMG(1, y0 - 10);
  STAGE_IMG(2, y0 - 9);
  {
    int f0 = t * 4;
    int qyy = f0 >> 10, qx = (f0 >> 6) & 15, qch = f0 & 63;
    *(uint2*)&qt[f0] =
      *(const uint2*)(qp + (size_t)(b * 4096 + (y0 + qyy) * 64 + x0g + qx) * 64 + qch);
  }
  asm volatile("s_waitcnt lgkmcnt(0)" ::: "memory");

  // af byte offsets within one dy-block of bst (lane-linear, coalesced)
  int afoff[2][2];
#pragma unroll
  for (int j = 0; j < 2; ++j)
#pragma unroll
    for (int w2 = 0; w2 < 2; ++w2)
      afoff[j][w2] = ((((2 * ntp + j) * 2 + w2) * 64) + l) * 16;

  f32x16 acc[2][2];
#pragma unroll
  for (int mf = 0; mf < 2; ++mf)
#pragma unroll
    for (int j = 0; j < 2; ++j)
#pragma unroll
      for (int q = 0; q < 16; ++q) acc[mf][j][q] = 0.f;

  for (int dy = 0; dy < 23; ++dy) {
    if (dy < 22) {
      asm volatile("s_waitcnt vmcnt(1)" ::: "memory");
    } else {
      asm volatile("s_waitcnt vmcnt(0)" ::: "memory");
    }
    __builtin_amdgcn_s_barrier();
    __builtin_amdgcn_sched_barrier(0);
    asm volatile("" ::: "memory");

    // stage img 3 ahead (slot not read in this barrier interval)
    if (dy < 21) STAGE_IMG((dy + 3) & 3, y0 + dy - 8);

    // af direct from global (L2-hit; compiler inserts the waits)
    const char* bdy = bstc + dy * 16384;
    bf16x8 af[2][2], bi[2][2];
#pragma unroll
    for (int j = 0; j < 2; ++j)
#pragma unroll
      for (int w2 = 0; w2 < 2; ++w2)
        af[j][w2] = *(const bf16x8*)(bdy + afoff[j][w2]);

    int rsl = (dy + yy) & 3;
#pragma unroll
    for (int mf = 0; mf < 2; ++mf) {
      int v = mf * 32 + (l & 31);
#pragma unroll
      for (int w2 = 0; w2 < 2; ++w2)
        bi[mf][w2] = *(const bf16x8*)(&img[rsl][v][((o1_8 + w2 * 2 + hh) ^ (v & 7)) * 8]);
    }
#pragma unroll
    for (int w2 = 0; w2 < 2; ++w2)
#pragma unroll
      for (int j = 0; j < 2; ++j) {
        acc[0][j] = __builtin_amdgcn_mfma_f32_32x32x16_bf16(af[j][w2], bi[0][w2], acc[0][j], 0, 0, 0);
        acc[1][j] = __builtin_amdgcn_mfma_f32_32x32x16_bf16(af[j][w2], bi[1][w2], acc[1][j], 0, 0, 0);
      }
  }
#undef STAGE_IMG

  // ---- fused epilogue: Y = sum_k q*(Lc + Lp), k lives in acc reg index ----
  float lc[2][16];
#pragma unroll
  for (int mf = 0; mf < 2; ++mf)
#pragma unroll
    for (int r = 0; r < 16; ++r) {
      int k = (r & 3) + 8 * ((r >> 2) & 1) + 4 * hh;
      lc[mf][r] = lcb[k * 64 + mf * 32 + (l & 31)];
    }
  size_t obase = ((size_t)b * 4096 + (y0 + yy) * 64 + x0g) * 256;
#pragma unroll
  for (int j = 0; j < 2; ++j) {
#pragma unroll
    for (int xh = 0; xh < 2; ++xh) {
      int x_local = 2 * (2 * ntp + j) + xh;
      const u16* qrow = &qt[(yy * 16 + x_local) * 64];
#pragma unroll
      for (int h = 0; h < 4; ++h) {
        float s0 = 0.f, s1 = 0.f;
#pragma unroll
        for (int r8 = 0; r8 < 8; ++r8) {
          int r = xh * 8 + r8;
          int k = (r8 & 3) + 8 * (r8 >> 2) + 4 * hh;
          float qv = (float)(*(const __bf16*)&qrow[h * 16 + k]);   // LDS broadcast
          s0 += qv * (acc[0][j][r] + lc[0][r]);
          s1 += qv * (acc[1][j][r] + lc[1][r]);
        }
        s0 += __shfl_xor(s0, 32);
        s1 += __shfl_xor(s1, 32);
        float val = (l >= 32) ? s1 : s0;           // ch = h*64 + l, v = l
        out[obase + (size_t)x_local * 256 + h * 64 + l] = val;
      }
    }
  }
}

extern "C" void kernel_launch(void* const* d_in, const int* in_sizes, int n_in,
                              void* d_out, int out_size, void* d_ws, size_t ws_size,
                              hipStream_t stream) {
  const float* x   = (const float*)d_in[0];
  const float* Wq  = (const float*)d_in[1];
  const float* Wk  = (const float*)d_in[2];
  const float* Wv  = (const float*)d_in[3];
  const float* gq  = (const float*)d_in[4];
  const float* bq  = (const float*)d_in[5];
  const float* mq  = (const float*)d_in[6];
  const float* vq  = (const float*)d_in[7];
  const float* gv  = (const float*)d_in[8];
  const float* bv  = (const float*)d_in[9];
  const float* mv  = (const float*)d_in[10];
  const float* vvr = (const float*)d_in[11];
  const float* pw  = (const float*)d_in[12];
  const float* pb  = (const float*)d_in[13];
  char* ws = (char*)d_ws;
  float* out = (float*)d_out;

  hipLaunchKernelGGL(kP, dim3(168), dim3(256), 0, stream,
                     Wq, Wk, Wv, gq, bq, mq, vq, gv, bv, mv, vvr, pw, ws);
  hipLaunchKernelGGL(kA, dim3(1024), dim3(256), 0, stream, x, ws);
  hipLaunchKernelGGL(kB1, dim3(256), dim3(256), 0, stream, ws);
  hipLaunchKernelGGL(kB2, dim3(1024), dim3(256), 0, stream, ws, pb);
  hipLaunchKernelGGL(kC, dim3(2048), dim3(512), 0, stream, ws, out);
}

// Round 19
// 172.693 us; speedup vs baseline: 14.7198x; 4.8958x over previous
//
#include <hip/hip_runtime.h>
#include <stdint.h>

typedef __bf16 bf16x8 __attribute__((ext_vector_type(8)));
typedef float  f32x4  __attribute__((ext_vector_type(4)));
typedef float  f32x16 __attribute__((ext_vector_type(16)));
typedef unsigned short u16;

// ---- workspace layout (bytes) ----
#define WCT_OFF   0u          // 144*256 bf16 = 73728   (W^T, fused Wq|Wk|Wv)
#define SC_OFF    73728u      // 144 f32 BN scale
#define SH_OFF    74304u      // 144 f32 BN shift
#define BST_OFF   75008u      // 23 * 16384 B (2-window conv B frags, frag-lane order)
#define ZB_OFF    524288u     // 4096 B of zeros (OOB guard for img staging)
#define MSUM_OFF  640256u     // 16*16*2 f32 (softmax max, 1/sum)
#define LCB_OFF   642304u     // 16*16*64 f32 (Lc + pos_b)
#define QP_OFF    707840u     // 16*4096*64 bf16 (q, BN'd, [b][pos][ch])
#define KT_OFF    9096448u    // 16*16*4096 bf16 (k, [b][ch][pos])
#define VT_OFF    11193600u   // 16*64*4096 bf16 (v, BN'd, [b][ch][pos] = per-v image)
#define P_OFF     19582208u   // 16*16*4096 bf16 (unnormalized softmax exp)

// ------------------------------------------------------------------
// Kernel P (parallelized): grid 168.
// ------------------------------------------------------------------
__global__ void kP(const float* Wq, const float* Wk, const float* Wv,
                   const float* gq, const float* bq, const float* mq, const float* vq,
                   const float* gv, const float* bv, const float* mv, const float* vvar,
                   const float* pw, char* ws) {
  int t = threadIdx.x;
  int blk = blockIdx.x;
  if (blk < 144) {
    int n = blk, c = t;
    float val;
    if (n < 64)      val = Wq[c * 64 + n];
    else if (n < 80) val = Wk[c * 16 + (n - 64)];
    else             val = Wv[c * 64 + (n - 80)];
    ((__bf16*)(ws + WCT_OFF))[n * 256 + c] = (__bf16)val;
  } else if (blk == 144) {
    if (t < 144) {
      float s, sh;
      if (t < 64)      { s = gq[t] * rsqrtf(vq[t] + 1e-3f); sh = bq[t] - mq[t] * s; }
      else if (t < 80) { s = 1.f; sh = 0.f; }
      else { int i = t - 80; s = gv[i] * rsqrtf(vvar[i] + 1e-3f); sh = bv[i] - mv[i] * s; }
      ((float*)(ws + SC_OFF))[t] = s;
      ((float*)(ws + SH_OFF))[t] = sh;
    }
    f32x4 fz;
    fz[0] = 0.f; fz[1] = 0.f; fz[2] = 0.f; fz[3] = 0.f;
    *(f32x4*)(ws + ZB_OFF + t * 16) = fz;     // 256*16 = 4096 B of zeros
  } else {
    int dy = blk - 145;                    // 0..22
    __bf16* bst = (__bf16*)(ws + BST_OFF) + dy * 8192;
    for (int i = 0; i < 32; ++i) {
      int idx = i * 256 + t;               // < 8192
      int nt = idx >> 10;
      int w2 = (idx >> 9) & 1;
      int l  = (idx >> 3) & 63;
      int e  = idx & 7;
      int n  = nt * 32 + (l & 31);
      int xr = n >> 4, kch = n & 15;
      int o1 = (2 * nt + 5) & ~7;
      int j  = o1 + w2 * 16 + (l >> 5) * 8 + e;
      int dxw = j - xr - 5;
      float val = (dxw >= 0 && dxw < 23) ? pw[(dy * 23 + dxw) * 16 + kch] : 0.f;
      bst[idx] = (__bf16)val;
    }
  }
}

// ------------------------------------------------------------------
// Kernel A: fused q/k/v projections + BN, MFMA 16x16x32.
// Grid 1024, M=64/block (4 blocks/CU).
// ------------------------------------------------------------------
__global__ __launch_bounds__(256) void kA(const float* x, char* ws) {
  __shared__ __align__(16) u16 qlds[64 * 72];   // 64 pos x 64ch (pad 72), 9216B
  int t = threadIdx.x, w = t >> 6, l = t & 63;
  int m0 = blockIdx.x * 64;
  int b = m0 >> 12;
  int posb = m0 & 4095;
  const __bf16* wct = (const __bf16*)(ws + WCT_OFF);
  const float* sc = (const float*)(ws + SC_OFF);
  const float* sh = (const float*)(ws + SH_OFF);
  __bf16* qp = (__bf16*)(ws + QP_OFF);
  __bf16* kt = (__bf16*)(ws + KT_OFF);
  __bf16* vt = (__bf16*)(ws + VT_OFF);

  int rl = l & 15;
  int kg = l >> 4;

  f32x4 acc[9];
#pragma unroll
  for (int nf = 0; nf < 9; ++nf)
#pragma unroll
    for (int q = 0; q < 4; ++q) acc[nf][q] = 0.f;

  for (int ks = 0; ks < 8; ++ks) {
    int m = m0 + w * 16 + rl;
    const float* xp = x + (size_t)m * 256 + ks * 32 + kg * 8;
    f32x4 v0 = *(const f32x4*)xp;
    f32x4 v1 = *(const f32x4*)(xp + 4);
    bf16x8 a;
    a[0] = (__bf16)v0[0]; a[1] = (__bf16)v0[1]; a[2] = (__bf16)v0[2]; a[3] = (__bf16)v0[3];
    a[4] = (__bf16)v1[0]; a[5] = (__bf16)v1[1]; a[6] = (__bf16)v1[2]; a[7] = (__bf16)v1[3];
#pragma unroll
    for (int nf = 0; nf < 9; ++nf) {
      bf16x8 bfr = *(const bf16x8*)(wct + (nf * 16 + rl) * 256 + ks * 32 + kg * 8);
      acc[nf] = __builtin_amdgcn_mfma_f32_16x16x32_bf16(a, bfr, acc[nf], 0, 0, 0);
    }
  }

#pragma unroll
  for (int nf = 0; nf < 9; ++nf) {
    int ch = nf * 16 + rl;
    float s = sc[ch], shv = sh[ch];
    int pbase = w * 16 + kg * 4;
    union { __bf16 h[4]; uint2 u; } pk;
#pragma unroll
    for (int r = 0; r < 4; ++r) pk.h[r] = (__bf16)(acc[nf][r] * s + shv);
    if (ch < 64) {
#pragma unroll
      for (int r = 0; r < 4; ++r)
        qlds[(pbase + r) * 72 + ch] = ((u16*)&pk.h[r])[0];
    } else if (ch < 80) {
      *(uint2*)(kt + (size_t)(b * 16 + ch - 64) * 4096 + posb + pbase) = pk.u;
    } else {
      *(uint2*)(vt + (size_t)(b * 64 + ch - 80) * 4096 + posb + pbase) = pk.u;
    }
  }
  __syncthreads();
  // dense readback: 512 chunks of 8 bf16
#pragma unroll
  for (int i = 0; i < 2; ++i) {
    int chunk = t + i * 256;
    int row = chunk >> 3, seg = chunk & 7;
    bf16x8 vq_ = *(const bf16x8*)(qlds + row * 72 + seg * 8);
    *(bf16x8*)(qp + (size_t)(b * 4096 + posb + row) * 64 + seg * 8) = vq_;
  }
}

// ------------------------------------------------------------------
// Kernel B1: per (b, k-channel) softmax max & 1/sum over 4096 positions.
// Also stores unnormalized P = exp(kt - mx) as bf16 (computed once).
// ------------------------------------------------------------------
__global__ void kB1(char* ws) {
  __shared__ float red[256];
  int t = threadIdx.x;
  int b = blockIdx.x >> 4, kk = blockIdx.x & 15;
  const __bf16* kt = (const __bf16*)(ws + KT_OFF) + (size_t)(b * 16 + kk) * 4096;
  __bf16* P = (__bf16*)(ws + P_OFF) + (size_t)(b * 16 + kk) * 4096;
  float v[16];
  bf16x8 c0 = *(const bf16x8*)(kt + t * 16);
  bf16x8 c1 = *(const bf16x8*)(kt + t * 16 + 8);
#pragma unroll
  for (int i = 0; i < 8; ++i) { v[i] = (float)c0[i]; v[8 + i] = (float)c1[i]; }
  float mx = v[0];
#pragma unroll
  for (int i = 1; i < 16; ++i) mx = fmaxf(mx, v[i]);
  red[t] = mx; __syncthreads();
  for (int s = 128; s > 0; s >>= 1) { if (t < s) red[t] = fmaxf(red[t], red[t + s]); __syncthreads(); }
  mx = red[0]; __syncthreads();
  float se = 0.f;
  union { __bf16 h[8]; uint4 u; } p0, p1;
#pragma unroll
  for (int i = 0; i < 8; ++i) { float e = expf(v[i] - mx); se += e; p0.h[i] = (__bf16)e; }
#pragma unroll
  for (int i = 0; i < 8; ++i) { float e = expf(v[8 + i] - mx); se += e; p1.h[i] = (__bf16)e; }
  *(uint4*)(P + t * 16) = p0.u;
  *(uint4*)(P + t * 16 + 8) = p1.u;
  red[t] = se; __syncthreads();
  for (int s = 128; s > 0; s >>= 1) { if (t < s) red[t] += red[t + s]; __syncthreads(); }
  if (t == 0) {
    float* ms = (float*)(ws + MSUM_OFF);
    ms[(b * 16 + kk) * 2] = mx;
    ms[(b * 16 + kk) * 2 + 1] = 1.f / red[0];
  }
}

// ------------------------------------------------------------------
// Kernel B2: LcB[b][k][v] = (sum_n P[k][n]*v[v][n]) * rsum + pos_b[k]
// ------------------------------------------------------------------
__global__ __launch_bounds__(256) void kB2(char* ws, const float* pos_b) {
  __shared__ float red[16][256];
  int t = threadIdx.x;
  int b = blockIdx.x >> 6, v = blockIdx.x & 63;
  const __bf16* P = (const __bf16*)(ws + P_OFF) + (size_t)b * 16 * 4096;
  const __bf16* vt = (const __bf16*)(ws + VT_OFF) + (size_t)(b * 64 + v) * 4096;
  const float* ms = (const float*)(ws + MSUM_OFF) + b * 32;
  float acc[16];
#pragma unroll
  for (int i = 0; i < 16; ++i) acc[i] = 0.f;
  for (int c = 0; c < 16; ++c) {
    int p = c * 256 + t;
    float vv = (float)vt[p];
#pragma unroll
    for (int i = 0; i < 16; ++i)
      acc[i] += (float)P[i * 4096 + p] * vv;
  }
#pragma unroll
  for (int i = 0; i < 16; ++i) red[i][t] = acc[i];
  __syncthreads();
  for (int s = 128; s > 0; s >>= 1) {
    if (t < s) {
#pragma unroll
      for (int i = 0; i < 16; ++i) red[i][t] += red[i][t + s];
    }
    __syncthreads();
  }
  if (t < 16) {
    float* lcb = (float*)(ws + LCB_OFF);
    lcb[(b * 16 + t) * 64 + v] = red[t][0] * ms[2 * t + 1] + pos_b[t];
  }
}

// ------------------------------------------------------------------
// Kernel C (FUSED conv + combine), R19 = exact R16 (measured best):
// 2-dy unrolled intervals, 7-slot img ring, (512,4), af direct from L2.
// ------------------------------------------------------------------
__global__ __launch_bounds__(512, 4) void kC(char* ws, float* out) {
  __shared__ __align__(16) u16 img[7][64][64];    // 57344 B  [slot][v][col]
  __shared__ __align__(16) u16 qt[2048];          // 4096 B   [yy][x16][ch64]
  int t = threadIdx.x, w = t >> 6, l = t & 63;
  int bid = blockIdx.x;
  int swz = (bid & 7) * 256 + (bid >> 3);         // 2048 = 8 XCD x 256
  int b = swz >> 7;
  int rest = swz & 127;
  int yp = rest >> 2, xt = rest & 3;
  int y0 = yp * 2, x0g = xt * 16;
  const __bf16* vt  = (const __bf16*)(ws + VT_OFF);
  const __bf16* qp  = (const __bf16*)(ws + QP_OFF);
  const float*  lcb = (const float*)(ws + LCB_OFF) + b * 1024;
  const char*   bstc = (const char*)(ws + BST_OFF);
  const char*   zb   = (const char*)(ws + ZB_OFF) + (t & 255) * 16;

  int yy = w >> 2, ntp = w & 3;
  int hh = l >> 5;
  int o1_8 = ((4 * ntp + 5) & ~7) >> 3;    // shared window base / 8 for the nt-pair

  // img staging lane map: LDS linear [sv][sc8*8]; global chunk = sc8 ^ (sv&7)
  int sv = t >> 3, sc8 = t & 7;
  int sgx = x0g - 16 + (sc8 ^ (sv & 7)) * 8;
  bool sokx = (sgx >= 0 && sgx < 64);
  const char* vsrc = (const char*)(vt + (size_t)(b * 64 + sv) * 4096 + sgx);

#define STAGE_IMG(slot, rowv) do {                                             \
    int _r = (rowv);                                                           \
    const char* _s = (sokx && _r >= 0 && _r < 64) ? (vsrc + _r * 128) : zb;    \
    __builtin_amdgcn_global_load_lds(                                          \
      (const __attribute__((address_space(1))) void*)_s,                       \
      (__attribute__((address_space(3))) void*)((char*)&img[0][0][0] + (slot) * 8192 + w * 1024), \
      16, 0, 0);                                                               \
  } while (0)

  // ---- prologue: img ri=0..4 (rows y0-11..y0-7); q tile (ds_write drained) ----
  STAGE_IMG(0, y0 - 11);
  STAGE_IMG(1, y0 - 10);
  STAGE_IMG(2, y0 - 9);
  STAGE_IMG(3, y0 - 8);
  STAGE_IMG(4, y0 - 7);
  {
    int f0 = t * 4;
    int qyy = f0 >> 10, qx = (f0 >> 6) & 15, qch = f0 & 63;
    *(uint2*)&qt[f0] =
      *(const uint2*)(qp + (size_t)(b * 4096 + (y0 + qyy) * 64 + x0g + qx) * 64 + qch);
  }
  asm volatile("s_waitcnt lgkmcnt(0)" ::: "memory");

  // af byte offsets within one dy-block of bst (lane-linear, coalesced)
  int afoff[2][2];
#pragma unroll
  for (int j = 0; j < 2; ++j)
#pragma unroll
    for (int w2 = 0; w2 < 2; ++w2)
      afoff[j][w2] = ((((2 * ntp + j) * 2 + w2) * 64) + l) * 16;

  f32x16 acc[2][2];
#pragma unroll
  for (int mf = 0; mf < 2; ++mf)
#pragma unroll
    for (int j = 0; j < 2; ++j)
#pragma unroll
      for (int q = 0; q < 16; ++q) acc[mf][j][q] = 0.f;

  int sb = 0;                                     // (2i) % 7
  for (int i = 0; i < 11; ++i) {
    int dy0 = 2 * i;
    if (i < 10)      asm volatile("s_waitcnt vmcnt(2)" ::: "memory");
    else             asm volatile("s_waitcnt vmcnt(1)" ::: "memory");
    __builtin_amdgcn_s_barrier();
    __builtin_amdgcn_sched_barrier(0);
    asm volatile("" ::: "memory");

    // stage ri = 2i+5, 2i+6 (rows y0+2i-6, y0+2i-5), bounded ri<=23
    {
      int sA = sb + 5; if (sA >= 7) sA -= 7;
      int sB = sb + 6; if (sB >= 7) sB -= 7;
      if (i <= 9) STAGE_IMG(sA, y0 + dy0 - 6);
      if (i <= 8) STAGE_IMG(sB, y0 + dy0 - 5);
    }

    // af for both dy (lane-linear global, L2-resident)
    const char* bdy0 = bstc + dy0 * 16384;
    bf16x8 af0[2][2], af1[2][2], bi0[2][2], bi1[2][2];
#pragma unroll
    for (int j = 0; j < 2; ++j)
#pragma unroll
      for (int w2 = 0; w2 < 2; ++w2) {
        af0[j][w2] = *(const bf16x8*)(bdy0 + afoff[j][w2]);
        af1[j][w2] = *(const bf16x8*)(bdy0 + 16384 + afoff[j][w2]);
      }

    int rA = sb + yy;     if (rA >= 7) rA -= 7;   // slot for dy0+yy
    int rB = sb + 1 + yy; if (rB >= 7) rB -= 7;   // slot for dy0+1+yy
#pragma unroll
    for (int mf = 0; mf < 2; ++mf) {
      int v = mf * 32 + (l & 31);
      int sw = (v & 7);
#pragma unroll
      for (int w2 = 0; w2 < 2; ++w2) {
        int c = ((o1_8 + w2 * 2 + hh) ^ sw) * 8;
        bi0[mf][w2] = *(const bf16x8*)(&img[rA][v][c]);
        bi1[mf][w2] = *(const bf16x8*)(&img[rB][v][c]);
      }
    }
#pragma unroll
    for (int w2 = 0; w2 < 2; ++w2)
#pragma unroll
      for (int j = 0; j < 2; ++j) {
        acc[0][j] = __builtin_amdgcn_mfma_f32_32x32x16_bf16(af0[j][w2], bi0[0][w2], acc[0][j], 0, 0, 0);
        acc[1][j] = __builtin_amdgcn_mfma_f32_32x32x16_bf16(af0[j][w2], bi0[1][w2], acc[1][j], 0, 0, 0);
      }
#pragma unroll
    for (int w2 = 0; w2 < 2; ++w2)
#pragma unroll
      for (int j = 0; j < 2; ++j) {
        acc[0][j] = __builtin_amdgcn_mfma_f32_32x32x16_bf16(af1[j][w2], bi1[0][w2], acc[0][j], 0, 0, 0);
        acc[1][j] = __builtin_amdgcn_mfma_f32_32x32x16_bf16(af1[j][w2], bi1[1][w2], acc[1][j], 0, 0, 0);
      }
    sb += 2; if (sb >= 7) sb -= 7;
  }

  // tail: dy = 22
  {
    asm volatile("s_waitcnt vmcnt(0)" ::: "memory");
    __builtin_amdgcn_s_barrier();
    __builtin_amdgcn_sched_barrier(0);
    asm volatile("" ::: "memory");
    const char* bdy = bstc + 22 * 16384;
    bf16x8 af[2][2], bi[2][2];
#pragma unroll
    for (int j = 0; j < 2; ++j)
#pragma unroll
      for (int w2 = 0; w2 < 2; ++w2)
        af[j][w2] = *(const bf16x8*)(bdy + afoff[j][w2]);
    int rA = sb + yy; if (rA >= 7) rA -= 7;       // (22+yy) % 7
#pragma unroll
    for (int mf = 0; mf < 2; ++mf) {
      int v = mf * 32 + (l & 31);
      int sw = (v & 7);
#pragma unroll
      for (int w2 = 0; w2 < 2; ++w2)
        bi[mf][w2] = *(const bf16x8*)(&img[rA][v][((o1_8 + w2 * 2 + hh) ^ sw) * 8]);
    }
#pragma unroll
    for (int w2 = 0; w2 < 2; ++w2)
#pragma unroll
      for (int j = 0; j < 2; ++j) {
        acc[0][j] = __builtin_amdgcn_mfma_f32_32x32x16_bf16(af[j][w2], bi[0][w2], acc[0][j], 0, 0, 0);
        acc[1][j] = __builtin_amdgcn_mfma_f32_32x32x16_bf16(af[j][w2], bi[1][w2], acc[1][j], 0, 0, 0);
      }
  }
#undef STAGE_IMG

  // ---- fused epilogue: Y = sum_k q*(Lc + Lp), k lives in acc reg index ----
  float lc[2][16];
#pragma unroll
  for (int mf = 0; mf < 2; ++mf)
#pragma unroll
    for (int r = 0; r < 16; ++r) {
      int k = (r & 3) + 8 * ((r >> 2) & 1) + 4 * hh;
      lc[mf][r] = lcb[k * 64 + mf * 32 + (l & 31)];
    }
  size_t obase = ((size_t)b * 4096 + (y0 + yy) * 64 + x0g) * 256;
#pragma unroll
  for (int j = 0; j < 2; ++j) {
#pragma unroll
    for (int xh = 0; xh < 2; ++xh) {
      int x_local = 2 * (2 * ntp + j) + xh;
      const u16* qrow = &qt[(yy * 16 + x_local) * 64];
#pragma unroll
      for (int h = 0; h < 4; ++h) {
        float s0 = 0.f, s1 = 0.f;
#pragma unroll
        for (int r8 = 0; r8 < 8; ++r8) {
          int r = xh * 8 + r8;
          int k = (r8 & 3) + 8 * (r8 >> 2) + 4 * hh;
          float qv = (float)(*(const __bf16*)&qrow[h * 16 + k]);   // LDS broadcast
          s0 += qv * (acc[0][j][r] + lc[0][r]);
          s1 += qv * (acc[1][j][r] + lc[1][r]);
        }
        s0 += __shfl_xor(s0, 32);
        s1 += __shfl_xor(s1, 32);
        float val = (l >= 32) ? s1 : s0;           // ch = h*64 + l, v = l
        out[obase + (size_t)x_local * 256 + h * 64 + l] = val;
      }
    }
  }
}

extern "C" void kernel_launch(void* const* d_in, const int* in_sizes, int n_in,
                              void* d_out, int out_size, void* d_ws, size_t ws_size,
                              hipStream_t stream) {
  const float* x   = (const float*)d_in[0];
  const float* Wq  = (const float*)d_in[1];
  const float* Wk  = (const float*)d_in[2];
  const float* Wv  = (const float*)d_in[3];
  const float* gq  = (const float*)d_in[4];
  const float* bq  = (const float*)d_in[5];
  const float* mq  = (const float*)d_in[6];
  const float* vq  = (const float*)d_in[7];
  const float* gv  = (const float*)d_in[8];
  const float* bv  = (const float*)d_in[9];
  const float* mv  = (const float*)d_in[10];
  const float* vvr = (const float*)d_in[11];
  const float* pw  = (const float*)d_in[12];
  const float* pb  = (const float*)d_in[13];
  char* ws = (char*)d_ws;
  float* out = (float*)d_out;

  hipLaunchKernelGGL(kP, dim3(168), dim3(256), 0, stream,
                     Wq, Wk, Wv, gq, bq, mq, vq, gv, bv, mv, vvr, pw, ws);
  hipLaunchKernelGGL(kA, dim3(1024), dim3(256), 0, stream, x, ws);
  hipLaunchKernelGGL(kB1, dim3(256), dim3(256), 0, stream, ws);
  hipLaunchKernelGGL(kB2, dim3(1024), dim3(256), 0, stream, ws, pb);
  hipLaunchKernelGGL(kC, dim3(2048), dim3(512), 0, stream, ws, out);
}

// Round 20
// 168.225 us; speedup vs baseline: 15.1107x; 1.0266x over previous
//
#include <hip/hip_runtime.h>
#include <stdint.h>

typedef __bf16 bf16x8 __attribute__((ext_vector_type(8)));
typedef float  f32x4  __attribute__((ext_vector_type(4)));
typedef float  f32x16 __attribute__((ext_vector_type(16)));
typedef unsigned short u16;

// ---- workspace layout (bytes) ----
#define WCT_OFF   0u          // 144*256 bf16 = 73728   (W^T, fused Wq|Wk|Wv)
#define SC_OFF    73728u      // 144 f32 BN scale
#define SH_OFF    74304u      // 144 f32 BN shift
#define BST_OFF   75008u      // 23 * 16384 B (2-window conv B frags, frag-lane order)
#define ZB_OFF    524288u     // 4096 B of zeros (OOB guard for img staging)
#define MSUM_OFF  640256u     // 16*16*2 f32 (softmax max, 1/sum)
#define LCB_OFF   642304u     // 16*16*64 f32 (Lc + pos_b)
#define QP_OFF    707840u     // 16*4096*64 bf16 (q, BN'd, [b][pos][ch])
#define KT_OFF    9096448u    // 16*16*4096 bf16 (k, [b][ch][pos])
#define VT_OFF    11193600u   // 16*64*4096 bf16 (v, BN'd, [b][ch][pos] = per-v image)
#define P_OFF     19582208u   // 16*16*4096 bf16 (unnormalized softmax exp)

// ------------------------------------------------------------------
// Kernel P (parallelized): grid 168.
// ------------------------------------------------------------------
__global__ void kP(const float* Wq, const float* Wk, const float* Wv,
                   const float* gq, const float* bq, const float* mq, const float* vq,
                   const float* gv, const float* bv, const float* mv, const float* vvar,
                   const float* pw, char* ws) {
  int t = threadIdx.x;
  int blk = blockIdx.x;
  if (blk < 144) {
    int n = blk, c = t;
    float val;
    if (n < 64)      val = Wq[c * 64 + n];
    else if (n < 80) val = Wk[c * 16 + (n - 64)];
    else             val = Wv[c * 64 + (n - 80)];
    ((__bf16*)(ws + WCT_OFF))[n * 256 + c] = (__bf16)val;
  } else if (blk == 144) {
    if (t < 144) {
      float s, sh;
      if (t < 64)      { s = gq[t] * rsqrtf(vq[t] + 1e-3f); sh = bq[t] - mq[t] * s; }
      else if (t < 80) { s = 1.f; sh = 0.f; }
      else { int i = t - 80; s = gv[i] * rsqrtf(vvar[i] + 1e-3f); sh = bv[i] - mv[i] * s; }
      ((float*)(ws + SC_OFF))[t] = s;
      ((float*)(ws + SH_OFF))[t] = sh;
    }
    f32x4 fz;
    fz[0] = 0.f; fz[1] = 0.f; fz[2] = 0.f; fz[3] = 0.f;
    *(f32x4*)(ws + ZB_OFF + t * 16) = fz;     // 256*16 = 4096 B of zeros
  } else {
    int dy = blk - 145;                    // 0..22
    __bf16* bst = (__bf16*)(ws + BST_OFF) + dy * 8192;
    for (int i = 0; i < 32; ++i) {
      int idx = i * 256 + t;               // < 8192
      int nt = idx >> 10;
      int w2 = (idx >> 9) & 1;
      int l  = (idx >> 3) & 63;
      int e  = idx & 7;
      int n  = nt * 32 + (l & 31);
      int xr = n >> 4, kch = n & 15;
      int o1 = (2 * nt + 5) & ~7;
      int j  = o1 + w2 * 16 + (l >> 5) * 8 + e;
      int dxw = j - xr - 5;
      float val = (dxw >= 0 && dxw < 23) ? pw[(dy * 23 + dxw) * 16 + kch] : 0.f;
      bst[idx] = (__bf16)val;
    }
  }
}

// ------------------------------------------------------------------
// Kernel A: fused q/k/v projections + BN, MFMA 16x16x32.
// Grid 1024, M=64/block (4 blocks/CU).
// ------------------------------------------------------------------
__global__ __launch_bounds__(256) void kA(const float* x, char* ws) {
  __shared__ __align__(16) u16 qlds[64 * 72];   // 64 pos x 64ch (pad 72), 9216B
  int t = threadIdx.x, w = t >> 6, l = t & 63;
  int m0 = blockIdx.x * 64;
  int b = m0 >> 12;
  int posb = m0 & 4095;
  const __bf16* wct = (const __bf16*)(ws + WCT_OFF);
  const float* sc = (const float*)(ws + SC_OFF);
  const float* sh = (const float*)(ws + SH_OFF);
  __bf16* qp = (__bf16*)(ws + QP_OFF);
  __bf16* kt = (__bf16*)(ws + KT_OFF);
  __bf16* vt = (__bf16*)(ws + VT_OFF);

  int rl = l & 15;
  int kg = l >> 4;

  f32x4 acc[9];
#pragma unroll
  for (int nf = 0; nf < 9; ++nf)
#pragma unroll
    for (int q = 0; q < 4; ++q) acc[nf][q] = 0.f;

  for (int ks = 0; ks < 8; ++ks) {
    int m = m0 + w * 16 + rl;
    const float* xp = x + (size_t)m * 256 + ks * 32 + kg * 8;
    f32x4 v0 = *(const f32x4*)xp;
    f32x4 v1 = *(const f32x4*)(xp + 4);
    bf16x8 a;
    a[0] = (__bf16)v0[0]; a[1] = (__bf16)v0[1]; a[2] = (__bf16)v0[2]; a[3] = (__bf16)v0[3];
    a[4] = (__bf16)v1[0]; a[5] = (__bf16)v1[1]; a[6] = (__bf16)v1[2]; a[7] = (__bf16)v1[3];
#pragma unroll
    for (int nf = 0; nf < 9; ++nf) {
      bf16x8 bfr = *(const bf16x8*)(wct + (nf * 16 + rl) * 256 + ks * 32 + kg * 8);
      acc[nf] = __builtin_amdgcn_mfma_f32_16x16x32_bf16(a, bfr, acc[nf], 0, 0, 0);
    }
  }

#pragma unroll
  for (int nf = 0; nf < 9; ++nf) {
    int ch = nf * 16 + rl;
    float s = sc[ch], shv = sh[ch];
    int pbase = w * 16 + kg * 4;
    union { __bf16 h[4]; uint2 u; } pk;
#pragma unroll
    for (int r = 0; r < 4; ++r) pk.h[r] = (__bf16)(acc[nf][r] * s + shv);
    if (ch < 64) {
#pragma unroll
      for (int r = 0; r < 4; ++r)
        qlds[(pbase + r) * 72 + ch] = ((u16*)&pk.h[r])[0];
    } else if (ch < 80) {
      *(uint2*)(kt + (size_t)(b * 16 + ch - 64) * 4096 + posb + pbase) = pk.u;
    } else {
      *(uint2*)(vt + (size_t)(b * 64 + ch - 80) * 4096 + posb + pbase) = pk.u;
    }
  }
  __syncthreads();
  // dense readback: 512 chunks of 8 bf16
#pragma unroll
  for (int i = 0; i < 2; ++i) {
    int chunk = t + i * 256;
    int row = chunk >> 3, seg = chunk & 7;
    bf16x8 vq_ = *(const bf16x8*)(qlds + row * 72 + seg * 8);
    *(bf16x8*)(qp + (size_t)(b * 4096 + posb + row) * 64 + seg * 8) = vq_;
  }
}

// ------------------------------------------------------------------
// Kernel B1: per (b, k-channel) softmax max & 1/sum over 4096 positions.
// Also stores unnormalized P = exp(kt - mx) as bf16 (computed once).
// ------------------------------------------------------------------
__global__ void kB1(char* ws) {
  __shared__ float red[256];
  int t = threadIdx.x;
  int b = blockIdx.x >> 4, kk = blockIdx.x & 15;
  const __bf16* kt = (const __bf16*)(ws + KT_OFF) + (size_t)(b * 16 + kk) * 4096;
  __bf16* P = (__bf16*)(ws + P_OFF) + (size_t)(b * 16 + kk) * 4096;
  float v[16];
  bf16x8 c0 = *(const bf16x8*)(kt + t * 16);
  bf16x8 c1 = *(const bf16x8*)(kt + t * 16 + 8);
#pragma unroll
  for (int i = 0; i < 8; ++i) { v[i] = (float)c0[i]; v[8 + i] = (float)c1[i]; }
  float mx = v[0];
#pragma unroll
  for (int i = 1; i < 16; ++i) mx = fmaxf(mx, v[i]);
  red[t] = mx; __syncthreads();
  for (int s = 128; s > 0; s >>= 1) { if (t < s) red[t] = fmaxf(red[t], red[t + s]); __syncthreads(); }
  mx = red[0]; __syncthreads();
  float se = 0.f;
  union { __bf16 h[8]; uint4 u; } p0, p1;
#pragma unroll
  for (int i = 0; i < 8; ++i) { float e = expf(v[i] - mx); se += e; p0.h[i] = (__bf16)e; }
#pragma unroll
  for (int i = 0; i < 8; ++i) { float e = expf(v[8 + i] - mx); se += e; p1.h[i] = (__bf16)e; }
  *(uint4*)(P + t * 16) = p0.u;
  *(uint4*)(P + t * 16 + 8) = p1.u;
  red[t] = se; __syncthreads();
  for (int s = 128; s > 0; s >>= 1) { if (t < s) red[t] += red[t + s]; __syncthreads(); }
  if (t == 0) {
    float* ms = (float*)(ws + MSUM_OFF);
    ms[(b * 16 + kk) * 2] = mx;
    ms[(b * 16 + kk) * 2 + 1] = 1.f / red[0];
  }
}

// ------------------------------------------------------------------
// Kernel B2 (R20: MFMA-ized): Lc[k][v] = sum_pos P[k][pos]*vt[v][pos].
// Grid 64 = (b x vtile16). 4 waves split K=4096 into 1024-chunks
// (32 x mfma_16x16x32, A=P rows=k, B=vt rows=v, verified kA layout),
// 4KB LDS cross-wave reduce, then lcb = sum * rsum + pos_b (semantics
// unchanged -> kC untouched).
// ------------------------------------------------------------------
__global__ __launch_bounds__(256) void kB2(char* ws, const float* pos_b) {
  __shared__ float red[4][16][16];
  int t = threadIdx.x, w = t >> 6, l = t & 63;
  int b = blockIdx.x >> 2, vtile = blockIdx.x & 3;
  const __bf16* P  = (const __bf16*)(ws + P_OFF) + (size_t)b * 16 * 4096;
  const __bf16* vt = (const __bf16*)(ws + VT_OFF) + (size_t)(b * 64 + vtile * 16) * 4096;
  const float* ms = (const float*)(ws + MSUM_OFF) + b * 32;
  int ar = l & 15;          // A row (k) / B col (v)
  int kg = l >> 4;          // k-subgroup within K-step
  const __bf16* pA = P  + (size_t)ar * 4096 + w * 1024 + kg * 8;
  const __bf16* pB = vt + (size_t)ar * 4096 + w * 1024 + kg * 8;
  f32x4 acc;
  acc[0] = 0.f; acc[1] = 0.f; acc[2] = 0.f; acc[3] = 0.f;
#pragma unroll 4
  for (int ks = 0; ks < 32; ++ks) {
    bf16x8 a  = *(const bf16x8*)(pA + ks * 32);
    bf16x8 bb = *(const bf16x8*)(pB + ks * 32);
    acc = __builtin_amdgcn_mfma_f32_16x16x32_bf16(a, bb, acc, 0, 0, 0);
  }
  // C layout (verified): col(v) = l&15, row(k) = (l>>4)*4 + r
#pragma unroll
  for (int r = 0; r < 4; ++r)
    red[w][kg * 4 + r][ar] = acc[r];
  __syncthreads();
  int k = t >> 4, v = t & 15;
  float s = red[0][k][v] + red[1][k][v] + red[2][k][v] + red[3][k][v];
  ((float*)(ws + LCB_OFF))[(b * 16 + k) * 64 + vtile * 16 + v] =
      s * ms[2 * k + 1] + pos_b[k];
}

// ------------------------------------------------------------------
// Kernel C (FUSED conv + combine) = exact R16/R19 (measured best):
// 2-dy unrolled intervals, 7-slot img ring, (512,4), af direct from L2.
// ------------------------------------------------------------------
__global__ __launch_bounds__(512, 4) void kC(char* ws, float* out) {
  __shared__ __align__(16) u16 img[7][64][64];    // 57344 B  [slot][v][col]
  __shared__ __align__(16) u16 qt[2048];          // 4096 B   [yy][x16][ch64]
  int t = threadIdx.x, w = t >> 6, l = t & 63;
  int bid = blockIdx.x;
  int swz = (bid & 7) * 256 + (bid >> 3);         // 2048 = 8 XCD x 256
  int b = swz >> 7;
  int rest = swz & 127;
  int yp = rest >> 2, xt = rest & 3;
  int y0 = yp * 2, x0g = xt * 16;
  const __bf16* vt  = (const __bf16*)(ws + VT_OFF);
  const __bf16* qp  = (const __bf16*)(ws + QP_OFF);
  const float*  lcb = (const float*)(ws + LCB_OFF) + b * 1024;
  const char*   bstc = (const char*)(ws + BST_OFF);
  const char*   zb   = (const char*)(ws + ZB_OFF) + (t & 255) * 16;

  int yy = w >> 2, ntp = w & 3;
  int hh = l >> 5;
  int o1_8 = ((4 * ntp + 5) & ~7) >> 3;    // shared window base / 8 for the nt-pair

  // img staging lane map: LDS linear [sv][sc8*8]; global chunk = sc8 ^ (sv&7)
  int sv = t >> 3, sc8 = t & 7;
  int sgx = x0g - 16 + (sc8 ^ (sv & 7)) * 8;
  bool sokx = (sgx >= 0 && sgx < 64);
  const char* vsrc = (const char*)(vt + (size_t)(b * 64 + sv) * 4096 + sgx);

#define STAGE_IMG(slot, rowv) do {                                             \
    int _r = (rowv);                                                           \
    const char* _s = (sokx && _r >= 0 && _r < 64) ? (vsrc + _r * 128) : zb;    \
    __builtin_amdgcn_global_load_lds(                                          \
      (const __attribute__((address_space(1))) void*)_s,                       \
      (__attribute__((address_space(3))) void*)((char*)&img[0][0][0] + (slot) * 8192 + w * 1024), \
      16, 0, 0);                                                               \
  } while (0)

  // ---- prologue: img ri=0..4 (rows y0-11..y0-7); q tile (ds_write drained) ----
  STAGE_IMG(0, y0 - 11);
  STAGE_IMG(1, y0 - 10);
  STAGE_IMG(2, y0 - 9);
  STAGE_IMG(3, y0 - 8);
  STAGE_IMG(4, y0 - 7);
  {
    int f0 = t * 4;
    int qyy = f0 >> 10, qx = (f0 >> 6) & 15, qch = f0 & 63;
    *(uint2*)&qt[f0] =
      *(const uint2*)(qp + (size_t)(b * 4096 + (y0 + qyy) * 64 + x0g + qx) * 64 + qch);
  }
  asm volatile("s_waitcnt lgkmcnt(0)" ::: "memory");

  // af byte offsets within one dy-block of bst (lane-linear, coalesced)
  int afoff[2][2];
#pragma unroll
  for (int j = 0; j < 2; ++j)
#pragma unroll
    for (int w2 = 0; w2 < 2; ++w2)
      afoff[j][w2] = ((((2 * ntp + j) * 2 + w2) * 64) + l) * 16;

  f32x16 acc[2][2];
#pragma unroll
  for (int mf = 0; mf < 2; ++mf)
#pragma unroll
    for (int j = 0; j < 2; ++j)
#pragma unroll
      for (int q = 0; q < 16; ++q) acc[mf][j][q] = 0.f;

  int sb = 0;                                     // (2i) % 7
  for (int i = 0; i < 11; ++i) {
    int dy0 = 2 * i;
    if (i < 10)      asm volatile("s_waitcnt vmcnt(2)" ::: "memory");
    else             asm volatile("s_waitcnt vmcnt(1)" ::: "memory");
    __builtin_amdgcn_s_barrier();
    __builtin_amdgcn_sched_barrier(0);
    asm volatile("" ::: "memory");

    // stage ri = 2i+5, 2i+6 (rows y0+2i-6, y0+2i-5), bounded ri<=23
    {
      int sA = sb + 5; if (sA >= 7) sA -= 7;
      int sB = sb + 6; if (sB >= 7) sB -= 7;
      if (i <= 9) STAGE_IMG(sA, y0 + dy0 - 6);
      if (i <= 8) STAGE_IMG(sB, y0 + dy0 - 5);
    }

    // af for both dy (lane-linear global, L2-resident)
    const char* bdy0 = bstc + dy0 * 16384;
    bf16x8 af0[2][2], af1[2][2], bi0[2][2], bi1[2][2];
#pragma unroll
    for (int j = 0; j < 2; ++j)
#pragma unroll
      for (int w2 = 0; w2 < 2; ++w2) {
        af0[j][w2] = *(const bf16x8*)(bdy0 + afoff[j][w2]);
        af1[j][w2] = *(const bf16x8*)(bdy0 + 16384 + afoff[j][w2]);
      }

    int rA = sb + yy;     if (rA >= 7) rA -= 7;   // slot for dy0+yy
    int rB = sb + 1 + yy; if (rB >= 7) rB -= 7;   // slot for dy0+1+yy
#pragma unroll
    for (int mf = 0; mf < 2; ++mf) {
      int v = mf * 32 + (l & 31);
      int sw = (v & 7);
#pragma unroll
      for (int w2 = 0; w2 < 2; ++w2) {
        int c = ((o1_8 + w2 * 2 + hh) ^ sw) * 8;
        bi0[mf][w2] = *(const bf16x8*)(&img[rA][v][c]);
        bi1[mf][w2] = *(const bf16x8*)(&img[rB][v][c]);
      }
    }
#pragma unroll
    for (int w2 = 0; w2 < 2; ++w2)
#pragma unroll
      for (int j = 0; j < 2; ++j) {
        acc[0][j] = __builtin_amdgcn_mfma_f32_32x32x16_bf16(af0[j][w2], bi0[0][w2], acc[0][j], 0, 0, 0);
        acc[1][j] = __builtin_amdgcn_mfma_f32_32x32x16_bf16(af0[j][w2], bi0[1][w2], acc[1][j], 0, 0, 0);
      }
#pragma unroll
    for (int w2 = 0; w2 < 2; ++w2)
#pragma unroll
      for (int j = 0; j < 2; ++j) {
        acc[0][j] = __builtin_amdgcn_mfma_f32_32x32x16_bf16(af1[j][w2], bi1[0][w2], acc[0][j], 0, 0, 0);
        acc[1][j] = __builtin_amdgcn_mfma_f32_32x32x16_bf16(af1[j][w2], bi1[1][w2], acc[1][j], 0, 0, 0);
      }
    sb += 2; if (sb >= 7) sb -= 7;
  }

  // tail: dy = 22
  {
    asm volatile("s_waitcnt vmcnt(0)" ::: "memory");
    __builtin_amdgcn_s_barrier();
    __builtin_amdgcn_sched_barrier(0);
    asm volatile("" ::: "memory");
    const char* bdy = bstc + 22 * 16384;
    bf16x8 af[2][2], bi[2][2];
#pragma unroll
    for (int j = 0; j < 2; ++j)
#pragma unroll
      for (int w2 = 0; w2 < 2; ++w2)
        af[j][w2] = *(const bf16x8*)(bdy + afoff[j][w2]);
    int rA = sb + yy; if (rA >= 7) rA -= 7;       // (22+yy) % 7
#pragma unroll
    for (int mf = 0; mf < 2; ++mf) {
      int v = mf * 32 + (l & 31);
      int sw = (v & 7);
#pragma unroll
      for (int w2 = 0; w2 < 2; ++w2)
        bi[mf][w2] = *(const bf16x8*)(&img[rA][v][((o1_8 + w2 * 2 + hh) ^ sw) * 8]);
    }
#pragma unroll
    for (int w2 = 0; w2 < 2; ++w2)
#pragma unroll
      for (int j = 0; j < 2; ++j) {
        acc[0][j] = __builtin_amdgcn_mfma_f32_32x32x16_bf16(af[j][w2], bi[0][w2], acc[0][j], 0, 0, 0);
        acc[1][j] = __builtin_amdgcn_mfma_f32_32x32x16_bf16(af[j][w2], bi[1][w2], acc[1][j], 0, 0, 0);
      }
  }
#undef STAGE_IMG

  // ---- fused epilogue: Y = sum_k q*(Lc + Lp), k lives in acc reg index ----
  float lc[2][16];
#pragma unroll
  for (int mf = 0; mf < 2; ++mf)
#pragma unroll
    for (int r = 0; r < 16; ++r) {
      int k = (r & 3) + 8 * ((r >> 2) & 1) + 4 * hh;
      lc[mf][r] = lcb[k * 64 + mf * 32 + (l & 31)];
    }
  size_t obase = ((size_t)b * 4096 + (y0 + yy) * 64 + x0g) * 256;
#pragma unroll
  for (int j = 0; j < 2; ++j) {
#pragma unroll
    for (int xh = 0; xh < 2; ++xh) {
      int x_local = 2 * (2 * ntp + j) + xh;
      const u16* qrow = &qt[(yy * 16 + x_local) * 64];
#pragma unroll
      for (int h = 0; h < 4; ++h) {
        float s0 = 0.f, s1 = 0.f;
#pragma unroll
        for (int r8 = 0; r8 < 8; ++r8) {
          int r = xh * 8 + r8;
          int k = (r8 & 3) + 8 * (r8 >> 2) + 4 * hh;
          float qv = (float)(*(const __bf16*)&qrow[h * 16 + k]);   // LDS broadcast
          s0 += qv * (acc[0][j][r] + lc[0][r]);
          s1 += qv * (acc[1][j][r] + lc[1][r]);
        }
        s0 += __shfl_xor(s0, 32);
        s1 += __shfl_xor(s1, 32);
        float val = (l >= 32) ? s1 : s0;           // ch = h*64 + l, v = l
        out[obase + (size_t)x_local * 256 + h * 64 + l] = val;
      }
    }
  }
}

extern "C" void kernel_launch(void* const* d_in, const int* in_sizes, int n_in,
                              void* d_out, int out_size, void* d_ws, size_t ws_size,
                              hipStream_t stream) {
  const float* x   = (const float*)d_in[0];
  const float* Wq  = (const float*)d_in[1];
  const float* Wk  = (const float*)d_in[2];
  const float* Wv  = (const float*)d_in[3];
  const float* gq  = (const float*)d_in[4];
  const float* bq  = (const float*)d_in[5];
  const float* mq  = (const float*)d_in[6];
  const float* vq  = (const float*)d_in[7];
  const float* gv  = (const float*)d_in[8];
  const float* bv  = (const float*)d_in[9];
  const float* mv  = (const float*)d_in[10];
  const float* vvr = (const float*)d_in[11];
  const float* pw  = (const float*)d_in[12];
  const float* pb  = (const float*)d_in[13];
  char* ws = (char*)d_ws;
  float* out = (float*)d_out;

  hipLaunchKernelGGL(kP, dim3(168), dim3(256), 0, stream,
                     Wq, Wk, Wv, gq, bq, mq, vq, gv, bv, mv, vvr, pw, ws);
  hipLaunchKernelGGL(kA, dim3(1024), dim3(256), 0, stream, x, ws);
  hipLaunchKernelGGL(kB1, dim3(256), dim3(256), 0, stream, ws);
  hipLaunchKernelGGL(kB2, dim3(64), dim3(256), 0, stream, ws, pb);
  hipLaunchKernelGGL(kC, dim3(2048), dim3(512), 0, stream, ws, out);
}